// Round 4
// baseline (22014.621 us; speedup 1.0000x reference)
//
#include <hip/hip_runtime.h>
#include <cstdint>
#include <cstddef>
#include <math.h>

#define B_   32
#define S_   2048
#define IN_  128
#define H_   256
#define G4_  1024   // 4*H
#define Q_   16
#define M_   64

// ---- bf16 <-> f32 bit helpers (used only for the bf16-STORAGE fallback) ---
__device__ __forceinline__ float bf2f(unsigned short u) {
  unsigned int x = ((unsigned int)u) << 16;
  float f; __builtin_memcpy(&f, &x, 4); return f;
}
__device__ __forceinline__ unsigned short f2bf(float f) {
  unsigned int x; __builtin_memcpy(&x, &f, 4);
  unsigned int lsb = (x >> 16) & 1u;
  x += 0x7fffu + lsb;
  return (unsigned short)(x >> 16);
}

// typed loads/stores (float or bf16 storage), fp32 compute
__device__ __forceinline__ float ld1(const float* p) { return *p; }
__device__ __forceinline__ float ld1(const unsigned short* p) { return bf2f(*p); }
__device__ __forceinline__ void st1(float* p, float v) { *p = v; }
__device__ __forceinline__ void st1(unsigned short* p, float v) { *p = f2bf(v); }

__device__ __forceinline__ float4 ld4(const float* p) { return *(const float4*)p; }
__device__ __forceinline__ float4 ld4(const unsigned short* p) {
  ushort4 u = *(const ushort4*)p;   // 8B load
  float4 r; r.x = bf2f(u.x); r.y = bf2f(u.y); r.z = bf2f(u.z); r.w = bf2f(u.w);
  return r;
}
__device__ __forceinline__ void st4(float* p, float4 v) { *(float4*)p = v; }
__device__ __forceinline__ void st4(unsigned short* p, float4 v) {
  ushort4 u; u.x = f2bf(v.x); u.y = f2bf(v.y); u.z = f2bf(v.z); u.w = f2bf(v.w);
  *(ushort4*)p = u;
}

// ---------------------------------------------------------------------------
// LSTM recurrence with FUSED input projection (no xg buffer).
// Grid: 256 blocks = 32 groups (batch rows) x 8; 1 block/CU -> co-resident.
// Block owns 128 gate rows (4 gates x 32 cols). W_hh and W_ih slices live in
// VGPRs. x_t row double-buffered in LDS; xa_{t+1} computed during the
// inter-block spin (it doesn't depend on h). h exchanged via agent-scope
// double-buffered global buffer + per-group release/acquire counter.
// ---------------------------------------------------------------------------
template <int KI, typename XT, typename HT>
__global__ __launch_bounds__(256, 1) void lstm_rec(
    const XT* __restrict__ x,            // [B*S, KI]
    const float* __restrict__ Wih,       // [1024, KI] fp32
    const float* __restrict__ bih,       // [1024]
    const float* __restrict__ bhh,       // [1024]
    const float* __restrict__ Whh,       // [1024, 256] fp32
    HT* __restrict__ hout,               // [B*S, 256]
    float* __restrict__ hbuf,            // [2][32][256] fp32
    unsigned int* __restrict__ cnt)      // [32][32]
{
  const int f = blockIdx.x;
  const int n = (f >> 3) & 7;                // block-in-group
  const int b = (f >> 6) * 8 + (f & 7);      // batch row (XCD-swizzled)

  const int tid  = threadIdx.x;
  const int w    = tid >> 6;                 // gate 0..3 (i,f,g,o)
  const int l    = tid & 63;
  const int cl   = l >> 1;                   // col-in-slice 0..31
  const int half = l & 1;                    // K half

  __shared__ float h_sh[256];
  __shared__ float x_sh[2][KI];
  __shared__ float gates_sh[4][32];
  __shared__ float c_sh[32];

  h_sh[tid] = 0.0f;
  if (tid < 32) c_sh[tid] = 0.0f;

  const int grow = w * 256 + n * 32 + cl;    // global gate row

  // W_hh half-slice -> 32 float4 (128 VGPR)
  const float* wp = Whh + (size_t)grow * 256 + half * 128;
  float4 wf[32];
#pragma unroll
  for (int i = 0; i < 32; i++) wf[i] = ld4(wp + 4 * i);

  // W_ih half-slice -> NQ float4
  constexpr int KH = KI / 2, NQ = KH / 4;
  const float* ip = Wih + (size_t)grow * KI + half * KH;
  float4 wi[NQ];
#pragma unroll
  for (int i = 0; i < NQ; i++) wi[i] = ld4(ip + 4 * i);

  const float rb = (half == 0) ? (bih[grow] + bhh[grow]) : 0.0f;

  const XT* xrow = x + (size_t)b * S_ * KI;
  HT* houtp = hout + (size_t)b * S_ * H_ + n * 32;
  unsigned int* cp = cnt + b * 32;
  float* hb = hbuf + b * 256;                // parity adds +8192

  // pre-stage x_0, x_1; prefetch x_2 into register
  if (tid < KI) {
    x_sh[0][tid] = ld1(xrow + tid);
    x_sh[1][tid] = ld1(xrow + KI + tid);
  }
  float xreg = (tid < KI) ? ld1(xrow + (size_t)2 * KI + tid) : 0.0f;
  __syncthreads();

  // xa_0 (partial over this thread's K-half; rb folded into half 0)
  float xa;
  {
    const float* xb = &x_sh[0][half * KH];
    float4 s = {0, 0, 0, 0};
#pragma unroll
    for (int i = 0; i < NQ; i++) {
      float4 h4 = *(const float4*)(xb + 4 * i);
      s.x += wi[i].x * h4.x; s.y += wi[i].y * h4.y;
      s.z += wi[i].z * h4.z; s.w += wi[i].w * h4.w;
    }
    xa = (s.x + s.y) + (s.z + s.w) + rb;
  }

  bool dead = false;                         // set if co-residency ever breaks
  for (int t = 0; t < S_; ++t) {
    // A: recurrent dot over this thread's half of h
    const float* hsb = h_sh + half * 128;
    float4 s = {0, 0, 0, 0};
#pragma unroll
    for (int i = 0; i < 32; i++) {
      float4 h4 = *(const float4*)(hsb + 4 * i);   // broadcast reads (free)
      s.x += wf[i].x * h4.x; s.y += wf[i].y * h4.y;
      s.z += wf[i].z * h4.z; s.w += wf[i].w * h4.w;
    }
    float g = (s.x + s.y) + (s.z + s.w) + xa;
    g += __shfl_xor(g, 1);                   // combine K halves
    if (half == 0) gates_sh[w][cl] = g;
    __syncthreads();

    // D: pointwise LSTM cell on 32 threads
    if (tid < 32) {
      float gi = gates_sh[0][tid], gf = gates_sh[1][tid];
      float gg = gates_sh[2][tid], go = gates_sh[3][tid];
      float ig = 1.0f / (1.0f + expf(-gi));
      float fg = 1.0f / (1.0f + expf(-gf));
      float cg = tanhf(gg);
      float og = 1.0f / (1.0f + expf(-go));
      float cn = fg * c_sh[tid] + ig * cg;
      c_sh[tid] = cn;
      float hn = og * tanhf(cn);
      st1(houtp + (size_t)t * H_ + tid, hn);
      if (t < S_ - 1) {
        __hip_atomic_store(&hb[((t + 1) & 1) * 8192 + n * 32 + tid], hn,
                           __ATOMIC_RELAXED, __HIP_MEMORY_SCOPE_AGENT);
      }
    }
    if (t == S_ - 1) break;
    __syncthreads();                         // drain hbuf stores

    // H1: release as early as possible
    if (tid == 0 && !dead)
      __hip_atomic_fetch_add(cp, 1u, __ATOMIC_RELEASE, __HIP_MEMORY_SCOPE_AGENT);

    // E/F: overlap the cross-CU latency with next input projection + prefetch
    float xreg_n = 0.0f;
    if (tid < KI) {
      int tn = (t + 3 < S_) ? t + 3 : S_ - 1;
      xreg_n = ld1(xrow + (size_t)tn * KI + tid);
    }
    {
      const float* xb = &x_sh[(t + 1) & 1][half * KH];
      float4 s2 = {0, 0, 0, 0};
#pragma unroll
      for (int i = 0; i < NQ; i++) {
        float4 h4 = *(const float4*)(xb + 4 * i);
        s2.x += wi[i].x * h4.x; s2.y += wi[i].y * h4.y;
        s2.z += wi[i].z * h4.z; s2.w += wi[i].w * h4.w;
      }
      xa = (s2.x + s2.y) + (s2.z + s2.w) + rb;
    }

    // H2: acquire (bounded; never hard-hangs)
    if (tid == 0 && !dead) {
      const unsigned int target = 8u * (unsigned)(t + 1);
      unsigned int guard = 0;
      while (__hip_atomic_load(cp, __ATOMIC_ACQUIRE, __HIP_MEMORY_SCOPE_AGENT) < target) {
        __builtin_amdgcn_s_sleep(1);
        if (++guard >= (1u << 20)) { dead = true; break; }
      }
    }
    __syncthreads();
    // J: pull new h; rotate x double-buffer
    h_sh[tid] = __hip_atomic_load(&hb[((t + 1) & 1) * 8192 + tid],
                                  __ATOMIC_RELAXED, __HIP_MEMORY_SCOPE_AGENT);
    if (tid < KI) x_sh[t & 1][tid] = xreg;
    xreg = xreg_n;
    __syncthreads();
  }
}

// ---------------------------------------------------------------------------
// kNN memory read. One wave per token. Writes enh = qw * enhanced  [MT,256].
// lstm (= d_out scratch) is always fp32.
// ---------------------------------------------------------------------------
template <typename ST>
__global__ __launch_bounds__(256) void knn_enh(
    const float* __restrict__ lstm, const float* __restrict__ Wcq,
    const float* __restrict__ bcq, const float* __restrict__ keys,
    const float* __restrict__ vals, const float* __restrict__ qwp,
    ST* __restrict__ enh)
{
  const int tid  = threadIdx.x;
  const int wave = tid >> 6, lane = tid & 63;
  const int t = blockIdx.x * 4 + wave;

  __shared__ float xsh[4][256];
  __shared__ float qsh[4][16];

  const float* xrow = lstm + (size_t)t * H_;
  float4 x4 = ld4(xrow + lane * 4);
  *(float4*)&xsh[wave][lane * 4] = x4;
  __syncthreads();

  // q = tanh(W_cq @ x + b_cq): lane -> (j = lane&15, segment = lane>>4)
  const int j = lane & 15, seg = lane >> 4;
  const float* wrow = Wcq + j * H_ + seg * 64;
  const float* xseg = &xsh[wave][seg * 64];
  float p = 0.0f;
#pragma unroll
  for (int c = 0; c < 64; c += 4) {
    float4 w4 = ld4(wrow + c);
    p += w4.x * xseg[c] + w4.y * xseg[c + 1] + w4.z * xseg[c + 2] + w4.w * xseg[c + 3];
  }
  p += __shfl_xor(p, 16);
  p += __shfl_xor(p, 32);
  float q = tanhf(p + bcq[j]);

  float sq = q * q;
  sq += __shfl_xor(sq, 1); sq += __shfl_xor(sq, 2);
  sq += __shfl_xor(sq, 4); sq += __shfl_xor(sq, 8);
  float qn = q / (sqrtf(sq) + 1e-8f);
  if (lane < 16) qsh[wave][lane] = qn;
  __syncthreads();

  // cosine sims: lane m handles memory row m
  const int m = lane;
  const float* krow = keys + m * Q_;
  float kv[16]; float kn2 = 0.0f;
#pragma unroll
  for (int jj = 0; jj < 16; jj++) { kv[jj] = krow[jj]; kn2 += kv[jj] * kv[jj]; }
  float rn = 1.0f / (sqrtf(kn2) + 1e-8f);
  float sim = 0.0f;
#pragma unroll
  for (int jj = 0; jj < 16; jj++) sim += qsh[wave][jj] * kv[jj];
  sim *= rn;

  // top-3 by butterfly argmax (ties -> lower index, matches lax.top_k)
  float rem = sim;
  float tv[3]; int ti[3];
#pragma unroll
  for (int k = 0; k < 3; k++) {
    float v = rem; int idx = m;
#pragma unroll
    for (int d = 1; d < 64; d <<= 1) {
      float ov = __shfl_xor(v, d);
      int   oi = __shfl_xor(idx, d);
      if (ov > v || (ov == v && oi < idx)) { v = ov; idx = oi; }
    }
    tv[k] = v; ti[k] = idx;
    if (m == idx) rem = -INFINITY;
  }
  float tot = tv[0] + tv[1] + tv[2];

  float ex = 0, ey = 0, ez = 0, ew = 0;
#pragma unroll
  for (int k = 0; k < 3; k++) {
    float4 vv = ld4(vals + (size_t)ti[k] * H_ + lane * 4);
    ex += tv[k] * vv.x; ey += tv[k] * vv.y;
    ez += tv[k] * vv.z; ew += tv[k] * vv.w;
  }
  float inv = (tot > 0.0f) ? 1.0f / tot : 0.0f;
  const float qw = qwp[0];

  float4 o;
  o.x = qw * ex * inv; o.y = qw * ey * inv;
  o.z = qw * ez * inv; o.w = qw * ew * inv;
  st4(enh + (size_t)t * H_ + lane * 4, o);
}

// ---------------------------------------------------------------------------
// Final projection, IN-PLACE on io (= d_out):
// out[t][h] = sum_k cw*io[t][k]*W[h][k] + sum_k enh[t][k]*W[h][256+k] + b[h]
// One block per 64 rows; block computes ALL 256 output cols, reads only its
// own rows of io, writes them back after the K-loop -> in-place is race-free.
// ---------------------------------------------------------------------------
template <typename ST>
__global__ __launch_bounds__(256) void gemm_cat(
    float* __restrict__ io, const ST* __restrict__ A2,
    const float* __restrict__ Bw, const float* __restrict__ bias,
    const float* __restrict__ cwp)
{
  __shared__ float As[16][68];
  __shared__ float Bs[16][260];
  const int tid  = threadIdx.x;
  const int row0 = blockIdx.x * 64;
  const int tx = tid & 15, ty = tid >> 4;
  const int lr = tid >> 2;
  const int lk = (tid & 3) << 2;
  const float cw = cwp[0];

  float acc[4][16];
#pragma unroll
  for (int i = 0; i < 4; i++)
#pragma unroll
    for (int j = 0; j < 16; j++) acc[i][j] = 0.0f;

  for (int k0 = 0; k0 < 512; k0 += 16) {
    float4 av;
    if (k0 < 256) {
      av = ld4(io + (size_t)(row0 + lr) * 256 + k0 + lk);
      av.x *= cw; av.y *= cw; av.z *= cw; av.w *= cw;
    } else {
      av = ld4(A2 + (size_t)(row0 + lr) * 256 + (k0 - 256) + lk);
    }
    As[lk + 0][lr] = av.x; As[lk + 1][lr] = av.y;
    As[lk + 2][lr] = av.z; As[lk + 3][lr] = av.w;
    // stage B: thread tid owns output col n=tid, loads its 16 K-values
    const float* bp = Bw + (size_t)tid * 512 + k0;
#pragma unroll
    for (int q = 0; q < 4; q++) {
      float4 b4 = ld4(bp + 4 * q);
      Bs[4 * q + 0][tid] = b4.x; Bs[4 * q + 1][tid] = b4.y;
      Bs[4 * q + 2][tid] = b4.z; Bs[4 * q + 3][tid] = b4.w;
    }
    __syncthreads();
#pragma unroll
    for (int k = 0; k < 16; k++) {
      float4 a4 = *(const float4*)&As[k][ty << 2];
      float aa[4] = {a4.x, a4.y, a4.z, a4.w};
#pragma unroll
      for (int cc = 0; cc < 4; cc++) {
        float4 b4 = *(const float4*)&Bs[k][cc * 64 + (tx << 2)];
        float bb[4] = {b4.x, b4.y, b4.z, b4.w};
#pragma unroll
        for (int i = 0; i < 4; i++)
#pragma unroll
          for (int jj = 0; jj < 4; jj++) acc[i][cc * 4 + jj] += aa[i] * bb[jj];
      }
    }
    __syncthreads();
  }

#pragma unroll
  for (int i = 0; i < 4; i++) {
#pragma unroll
    for (int cc = 0; cc < 4; cc++) {
      int c0 = cc * 64 + (tx << 2);
      float4 o;
      o.x = acc[i][cc * 4 + 0] + bias[c0 + 0];
      o.y = acc[i][cc * 4 + 1] + bias[c0 + 1];
      o.z = acc[i][cc * 4 + 2] + bias[c0 + 2];
      o.w = acc[i][cc * 4 + 3] + bias[c0 + 3];
      st4(io + (size_t)(row0 + (ty << 2) + i) * 256 + c0, o);
    }
  }
}

// ---------------------------------------------------------------------------
template <typename ST>
static void run_all(const float* x, const float* Wih0, const float* Whh0,
                    const float* bih0, const float* bhh0, const float* Wih1,
                    const float* Whh1, const float* bih1, const float* bhh1,
                    const float* Wcq, const float* bcq, const float* keys,
                    const float* vals, const float* Wout, const float* bout,
                    const float* cw, const float* qw, float* out,
                    void* d_ws, hipStream_t stream)
{
  // ws layout: [hbuf 2*32*256 f32][cnt 32*32 u32][pad][ST buffer MT*256]
  float* hbuf = (float*)d_ws;
  unsigned int* cnt = (unsigned int*)(hbuf + 2 * 32 * 256);
  ST* h1 = (ST*)((char*)d_ws + 72704);       // 69632 rounded up to 1KB+align
  const size_t sync_bytes = (size_t)(2 * 32 * 256) * 4 + 32 * 32 * 4;

  const int MT = B_ * S_;
  dim3 blk(256);

  hipMemsetAsync(hbuf, 0, sync_bytes, stream);
  lstm_rec<IN_, float, ST>
      <<<dim3(256), blk, 0, stream>>>(x, Wih0, bih0, bhh0, Whh0, h1, hbuf, cnt);

  hipMemsetAsync(hbuf, 0, sync_bytes, stream);
  lstm_rec<H_, ST, float>
      <<<dim3(256), blk, 0, stream>>>(h1, Wih1, bih1, bhh1, Whh1, out, hbuf, cnt);

  // enh reuses h1's region (h1 dead after layer-1 recurrence)
  knn_enh<ST><<<dim3(MT / 4), blk, 0, stream>>>(out, Wcq, bcq, keys, vals, qw, h1);

  gemm_cat<ST><<<dim3(MT / 64), blk, 0, stream>>>(out, h1, Wout, bout, cw);
}

extern "C" void kernel_launch(void* const* d_in, const int* in_sizes, int n_in,
                              void* d_out, int out_size, void* d_ws, size_t ws_size,
                              hipStream_t stream)
{
  // Reference dtypes are float32 throughout -> fp32 pointers (harness contract).
  const float* x    = (const float*)d_in[0];
  const float* Wih0 = (const float*)d_in[1];
  const float* Whh0 = (const float*)d_in[2];
  const float* bih0 = (const float*)d_in[3];
  const float* bhh0 = (const float*)d_in[4];
  const float* Wih1 = (const float*)d_in[5];
  const float* Whh1 = (const float*)d_in[6];
  const float* bih1 = (const float*)d_in[7];
  const float* bhh1 = (const float*)d_in[8];
  const float* Wcq  = (const float*)d_in[9];
  const float* bcq  = (const float*)d_in[10];
  const float* keys = (const float*)d_in[11];
  const float* vals = (const float*)d_in[12];
  const float* Wout = (const float*)d_in[13];
  const float* bout = (const float*)d_in[14];
  const float* cw   = (const float*)d_in[15];
  const float* qw   = (const float*)d_in[16];
  float* out = (float*)d_out;

  const size_t HE = (size_t)B_ * S_ * H_;    // 16,777,216 elements
  const size_t base = 72704;                  // sync block + alignment pad
  const size_t needF = base + HE * sizeof(float);          // ~67.2 MB
  const size_t needH = base + HE * sizeof(unsigned short); // ~33.6 MB

  if (ws_size >= needF) {
    run_all<float>(x, Wih0, Whh0, bih0, bhh0, Wih1, Whh1, bih1, bhh1, Wcq, bcq,
                   keys, vals, Wout, bout, cw, qw, out, d_ws, stream);
  } else if (ws_size >= needH) {
    run_all<unsigned short>(x, Wih0, Whh0, bih0, bhh0, Wih1, Whh1, bih1, bhh1,
                            Wcq, bcq, keys, vals, Wout, bout, cw, qw, out,
                            d_ws, stream);
  }
  // else: clean fail (output untouched) — tells us ws_size < 33.6 MB
}

// Round 6
// 15515.623 us; speedup vs baseline: 1.4189x; 1.4189x over previous
//
#include <hip/hip_runtime.h>
#include <cstdint>
#include <cstddef>
#include <math.h>

#define B_   32
#define S_   2048
#define IN_  128
#define H_   256
#define Q_   16
#define M_   64
#define D_   4      // layer-1 lag (LDS a-ring depth 8 > D+1)

__device__ __forceinline__ float4 ld4(const float* p) { return *(const float4*)p; }

#define AGLD(p)    __hip_atomic_load((p),  __ATOMIC_RELAXED, __HIP_MEMORY_SCOPE_AGENT)
#define AGST(p, v) __hip_atomic_store((p), (v), __ATOMIC_RELAXED, __HIP_MEMORY_SCOPE_AGENT)

// ---------------------------------------------------------------------------
// Fused 2-layer LSTM recurrence. 256 blocks = 32 rows x 8; 1 block/CU.
// Block owns 128 gate rows of EACH layer (4 gates x 32 cols).
// Whh0/Whh1/Wih0 slices in VGPRs (320 regs); Wih1 slice (128x256 fp32) in LDS
// (read only off the critical path: xa1 for step u+1 is computed during the
// exchange wait, since it depends on a_{u+1}, available D steps early).
// Cross-block exchange: tagged dword pairs (tag<<16 | fp32-half) in a
// parity-2 ring, agent-scope relaxed atomics -> single-round-trip sync.
// All-fp32 arithmetic (bf16 anywhere shifts kNN top-3 picks -> 0.46 absmax).
// ---------------------------------------------------------------------------
__global__ __launch_bounds__(256, 1) void lstm2(
    const float* __restrict__ x,     // [B,S,128]
    const float* __restrict__ Wih0, const float* __restrict__ bih0,
    const float* __restrict__ bhh0, const float* __restrict__ Whh0,
    const float* __restrict__ Wih1, const float* __restrict__ bih1,
    const float* __restrict__ bhh1, const float* __restrict__ Whh1,
    float* __restrict__ out,         // [B,S,256]  (= d_out, layer-1 hidden)
    unsigned int* __restrict__ ex)   // [32][2q][2p][2plane][256] tagged dwords
{
  const int f = blockIdx.x;
  const int n = (f >> 3) & 7;              // block-in-row
  const int b = (f >> 6) * 8 + (f & 7);    // row (XCD-swizzled)

  const int tid  = threadIdx.x;
  const int w    = tid >> 6;               // gate 0..3
  const int l    = tid & 63;
  const int cl   = l >> 1;                 // col-in-slice 0..31
  const int half = l & 1;                  // K half

  __shared__ float wih1_lds[128 * 257];    // 128 rows x 256 fp32, stride 257
  __shared__ float aring[8][256];          // last 8 layer-0 hidden vectors
  __shared__ float h_sh[256];              // layer-1 hidden h_{u-1}
  __shared__ float x_sh[2][IN_];
  __shared__ float g0_sh[4][32], g1_sh[4][32];

#pragma unroll
  for (int s2 = 0; s2 < 8; s2++) aring[s2][tid] = 0.0f;
  h_sh[tid] = 0.0f;

  const int grow = w * 256 + n * 32 + cl;

  // register-resident weights: Whh0/Whh1 half-rows + Wih0 half-row
  float4 wf0[32], wf1[32], wi0[16];
  {
    const float* p0  = Whh0 + (size_t)grow * 256 + half * 128;
    const float* p1  = Whh1 + (size_t)grow * 256 + half * 128;
    const float* pi0 = Wih0 + (size_t)grow * IN_ + half * 64;
#pragma unroll
    for (int i = 0; i < 32; i++) { wf0[i] = ld4(p0 + 4 * i); wf1[i] = ld4(p1 + 4 * i); }
#pragma unroll
    for (int i = 0; i < 16; i++) wi0[i] = ld4(pi0 + 4 * i);
  }
  // stage the block's Wih1 slice into LDS (fp32): thread -> row tid>>1, half tid&1
  {
    const int r = tid >> 1, hs = tid & 1;
    const int growR = (r >> 5) * 256 + n * 32 + (r & 31);
    const float* src = Wih1 + (size_t)growR * 256 + hs * 128;
    float* dst = wih1_lds + r * 257 + hs * 128;
#pragma unroll
    for (int i = 0; i < 32; i++) *(float4*)(dst + 4 * i) = ld4(src + 4 * i);
  }
  const float rb0 = (half == 0) ? (bih0[grow] + bhh0[grow]) : 0.0f;
  const float rb1 = (half == 0) ? (bih1[grow] + bhh1[grow]) : 0.0f;
  const float* wih1_row = wih1_lds + (w * 32 + cl) * 257 + half * 128;

  const float* xrow = x + (size_t)b * S_ * IN_;
  float* outp = out + (size_t)b * S_ * H_;
  unsigned int* exb = ex + (size_t)b * 2048;
  // addr(q,p,plane,e) = exb + (((q*2+p)*2+plane)<<8) + e

  if (tid < IN_) {
    x_sh[0][tid] = xrow[tid];
    x_sh[1][tid] = xrow[IN_ + tid];
  }
  float xreg = (tid < IN_) ? xrow[(size_t)2 * IN_ + tid] : 0.0f;
  float c0 = 0.0f, c1 = 0.0f;              // cell states (tid<32 / 64..95)
  float xa1 = 0.0f;                        // layer-1 input activation pipeline
  __syncthreads();

  // xa0 for t=0
  float xa0;
  {
    const float* xb = &x_sh[0][half * 64];
    float4 s = {0, 0, 0, 0};
#pragma unroll
    for (int i = 0; i < 16; i++) {
      float4 v = *(const float4*)(xb + 4 * i);
      s.x += wi0[i].x * v.x; s.y += wi0[i].y * v.y;
      s.z += wi0[i].z * v.z; s.w += wi0[i].w * v.w;
    }
    xa0 = (s.x + s.y) + (s.z + s.w) + rb0;
  }

  bool dead = false;
  for (int t = 0; t < S_ + D_; ++t) {
    const bool doA = (t < S_);
    const int  u   = t - D_;
    const bool doH = (u >= 0);

    // ---- 1. critical gate dots (register weights, broadcast LDS reads) --
    float g0 = 0.0f, g1 = 0.0f;
    if (doA) {
      const float* ap = &aring[(t - 1) & 7][half * 128];
      float4 s = {0, 0, 0, 0};
#pragma unroll
      for (int i = 0; i < 32; i++) {
        float4 v = *(const float4*)(ap + 4 * i);
        s.x += wf0[i].x * v.x; s.y += wf0[i].y * v.y;
        s.z += wf0[i].z * v.z; s.w += wf0[i].w * v.w;
      }
      g0 = (s.x + s.y) + (s.z + s.w) + xa0;
      g0 += __shfl_xor(g0, 1);
    }
    if (doH) {
      const float* hp = &h_sh[half * 128];
      float4 s = {0, 0, 0, 0};
#pragma unroll
      for (int i = 0; i < 32; i++) {
        float4 v = *(const float4*)(hp + 4 * i);
        s.x += wf1[i].x * v.x; s.y += wf1[i].y * v.y;
        s.z += wf1[i].z * v.z; s.w += wf1[i].w * v.w;
      }
      g1 = (s.x + s.y) + (s.z + s.w) + xa1;   // xa1 precomputed last iter
      g1 += __shfl_xor(g1, 1);
    }
    if (half == 0) {
      if (doA) g0_sh[w][cl] = g0;
      if (doH) g1_sh[w][cl] = g1;
    }
    __syncthreads();

    // ---- 2. cells + tagged publish (wave0: layer0, wave1: layer1) ------
    if (tid < 32 && doA) {
      float gi = g0_sh[0][tid], gf = g0_sh[1][tid];
      float gg = g0_sh[2][tid], go = g0_sh[3][tid];
      float ig = 1.0f / (1.0f + expf(-gi));
      float fg = 1.0f / (1.0f + expf(-gf));
      float cg = tanhf(gg);
      float og = 1.0f / (1.0f + expf(-go));
      c0 = fg * c0 + ig * cg;
      float a = og * tanhf(c0);
      unsigned bits = __float_as_uint(a);
      unsigned tag  = (unsigned)(t + 1) << 16;
      const int p = t & 1, e = n * 32 + tid;
      AGST(exb + (((0 * 2 + p) * 2 + 0) << 8) + e, tag | (bits >> 16));
      AGST(exb + (((0 * 2 + p) * 2 + 1) << 8) + e, tag | (bits & 0xffffu));
    } else if (tid >= 64 && tid < 96 && doH) {
      const int j = tid - 64;
      float gi = g1_sh[0][j], gf = g1_sh[1][j];
      float gg = g1_sh[2][j], go = g1_sh[3][j];
      float ig = 1.0f / (1.0f + expf(-gi));
      float fg = 1.0f / (1.0f + expf(-gf));
      float cg = tanhf(gg);
      float og = 1.0f / (1.0f + expf(-go));
      c1 = fg * c1 + ig * cg;
      float h = og * tanhf(c1);
      outp[(size_t)u * H_ + n * 32 + j] = h;      // plain store for epilogue
      unsigned bits = __float_as_uint(h);
      unsigned tag  = (unsigned)(u + 1) << 16;
      const int p = u & 1, e = n * 32 + j;
      AGST(exb + (((1 * 2 + p) * 2 + 0) << 8) + e, tag | (bits >> 16));
      AGST(exb + (((1 * 2 + p) * 2 + 1) << 8) + e, tag | (bits & 0xffffu));
    }

    // ---- 3. off-critical-path work (overlaps exchange latency) ---------
    // 3a. next xa0 from x_sh
    if (t + 1 < S_) {
      const float* xb = &x_sh[(t + 1) & 1][half * 64];
      float4 s = {0, 0, 0, 0};
#pragma unroll
      for (int i = 0; i < 16; i++) {
        float4 v = *(const float4*)(xb + 4 * i);
        s.x += wi0[i].x * v.x; s.y += wi0[i].y * v.y;
        s.z += wi0[i].z * v.z; s.w += wi0[i].w * v.w;
      }
      xa0 = (s.x + s.y) + (s.z + s.w) + rb0;
    }
    // 3b. xa1 for layer-1 step v = u+1 from LDS Wih1 x aring[v] (fp32!)
    {
      const int v = t - D_ + 1;
      if (v >= 0 && v < S_) {
        const float* av = &aring[v & 7][half * 128];
        float4 s = {0, 0, 0, 0};
#pragma unroll
        for (int i = 0; i < 32; i++) {
          float4 wv = *(const float4*)(wih1_row + 4 * i);
          float4 a4 = *(const float4*)(av + 4 * i);
          s.x += wv.x * a4.x; s.y += wv.y * a4.y;
          s.z += wv.z * a4.z; s.w += wv.w * a4.w;
        }
        xa1 = (s.x + s.y) + (s.z + s.w) + rb1;
      }
    }
    // 3c. x prefetch
    float xreg_n = 0.0f;
    if (tid < IN_ && t + 2 < S_) {
      int tn = (t + 3 < S_) ? t + 3 : S_ - 1;
      xreg_n = xrow[(size_t)tn * IN_ + tid];
    }

    // ---- 4. tagged gathers (single round trip) -------------------------
    if (!dead && (doA || doH)) {
      const unsigned eA = (unsigned)(t + 1) & 0xffffu;
      const unsigned eH = (unsigned)(u + 1) & 0xffffu;
      const int pa = t & 1, ph = u & 1;
      unsigned int* aHi = exb + (((0 * 2 + pa) * 2 + 0) << 8) + tid;
      unsigned int* aLo = exb + (((0 * 2 + pa) * 2 + 1) << 8) + tid;
      unsigned int* hHi = exb + (((1 * 2 + ph) * 2 + 0) << 8) + tid;
      unsigned int* hLo = exb + (((1 * 2 + ph) * 2 + 1) << 8) + tid;
      unsigned a0v = 0, a1v = 0, h0v = 0, h1v = 0;
      bool needA = doA, needH = doH;
      unsigned guard = 0;
      while (true) {
        if (needA) {
          a0v = AGLD(aHi); a1v = AGLD(aLo);
          if ((a0v >> 16) == eA && (a1v >> 16) == eA) needA = false;
        }
        if (needH) {
          h0v = AGLD(hHi); h1v = AGLD(hLo);
          if ((h0v >> 16) == eH && (h1v >> 16) == eH) needH = false;
        }
        if (!needA && !needH) break;
        if (++guard >= (1u << 20)) { dead = true; break; }
      }
      if (doA) aring[t & 7][tid] = __uint_as_float((a0v << 16) | (a1v & 0xffffu));
      if (doH) h_sh[tid]         = __uint_as_float((h0v << 16) | (h1v & 0xffffu));
    }
    if (tid < IN_ && t < S_) x_sh[t & 1][tid] = xreg;
    xreg = xreg_n;
    __syncthreads();
  }
}

// ---------------------------------------------------------------------------
// kNN memory read. One wave per token. enh = qw * enhanced  [MT,256] fp32.
// ---------------------------------------------------------------------------
__global__ __launch_bounds__(256) void knn_enh(
    const float* __restrict__ lstm, const float* __restrict__ Wcq,
    const float* __restrict__ bcq, const float* __restrict__ keys,
    const float* __restrict__ vals, const float* __restrict__ qwp,
    float* __restrict__ enh)
{
  const int tid  = threadIdx.x;
  const int wave = tid >> 6, lane = tid & 63;
  const int t = blockIdx.x * 4 + wave;

  __shared__ float xsh[4][256];
  __shared__ float qsh[4][16];

  const float* xrow = lstm + (size_t)t * H_;
  float4 x4 = ld4(xrow + lane * 4);
  *(float4*)&xsh[wave][lane * 4] = x4;
  __syncthreads();

  const int j = lane & 15, seg = lane >> 4;
  const float* wrow = Wcq + j * H_ + seg * 64;
  const float* xseg = &xsh[wave][seg * 64];
  float p = 0.0f;
#pragma unroll
  for (int c = 0; c < 64; c += 4) {
    float4 w4 = ld4(wrow + c);
    p += w4.x * xseg[c] + w4.y * xseg[c + 1] + w4.z * xseg[c + 2] + w4.w * xseg[c + 3];
  }
  p += __shfl_xor(p, 16);
  p += __shfl_xor(p, 32);
  float q = tanhf(p + bcq[j]);

  float sq = q * q;
  sq += __shfl_xor(sq, 1); sq += __shfl_xor(sq, 2);
  sq += __shfl_xor(sq, 4); sq += __shfl_xor(sq, 8);
  float qn = q / (sqrtf(sq) + 1e-8f);
  if (lane < 16) qsh[wave][lane] = qn;
  __syncthreads();

  const int m = lane;
  const float* krow = keys + m * Q_;
  float kv[16]; float kn2 = 0.0f;
#pragma unroll
  for (int jj = 0; jj < 16; jj++) { kv[jj] = krow[jj]; kn2 += kv[jj] * kv[jj]; }
  float rn = 1.0f / (sqrtf(kn2) + 1e-8f);
  float sim = 0.0f;
#pragma unroll
  for (int jj = 0; jj < 16; jj++) sim += qsh[wave][jj] * kv[jj];
  sim *= rn;

  float rem = sim;
  float tv[3]; int ti[3];
#pragma unroll
  for (int k = 0; k < 3; k++) {
    float v = rem; int idx = m;
#pragma unroll
    for (int d = 1; d < 64; d <<= 1) {
      float ov = __shfl_xor(v, d);
      int   oi = __shfl_xor(idx, d);
      if (ov > v || (ov == v && oi < idx)) { v = ov; idx = oi; }
    }
    tv[k] = v; ti[k] = idx;
    if (m == idx) rem = -INFINITY;
  }
  float tot = tv[0] + tv[1] + tv[2];

  float ex = 0, ey = 0, ez = 0, ew = 0;
#pragma unroll
  for (int k = 0; k < 3; k++) {
    float4 vv = ld4(vals + (size_t)ti[k] * H_ + lane * 4);
    ex += tv[k] * vv.x; ey += tv[k] * vv.y;
    ez += tv[k] * vv.z; ew += tv[k] * vv.w;
  }
  float inv = (tot > 0.0f) ? 1.0f / tot : 0.0f;
  const float qw = qwp[0];

  float4 o;
  o.x = qw * ex * inv; o.y = qw * ey * inv;
  o.z = qw * ez * inv; o.w = qw * ew * inv;
  *(float4*)&enh[(size_t)t * H_ + lane * 4] = o;
}

// ---------------------------------------------------------------------------
// Final projection, IN-PLACE on io (= d_out). Block owns 64 rows x all 256
// cols; reads its own rows, writes after the K-loop -> race-free in-place.
// ---------------------------------------------------------------------------
__global__ __launch_bounds__(256) void gemm_cat(
    float* __restrict__ io, const float* __restrict__ A2,
    const float* __restrict__ Bw, const float* __restrict__ bias,
    const float* __restrict__ cwp)
{
  __shared__ float As[16][68];
  __shared__ float Bs[16][260];
  const int tid  = threadIdx.x;
  const int row0 = blockIdx.x * 64;
  const int tx = tid & 15, ty = tid >> 4;
  const int lr = tid >> 2;
  const int lk = (tid & 3) << 2;
  const float cw = cwp[0];

  float acc[4][16];
#pragma unroll
  for (int i = 0; i < 4; i++)
#pragma unroll
    for (int j = 0; j < 16; j++) acc[i][j] = 0.0f;

  for (int k0 = 0; k0 < 512; k0 += 16) {
    float4 av;
    if (k0 < 256) {
      av = ld4(io + (size_t)(row0 + lr) * 256 + k0 + lk);
      av.x *= cw; av.y *= cw; av.z *= cw; av.w *= cw;
    } else {
      av = ld4(A2 + (size_t)(row0 + lr) * 256 + (k0 - 256) + lk);
    }
    As[lk + 0][lr] = av.x; As[lk + 1][lr] = av.y;
    As[lk + 2][lr] = av.z; As[lk + 3][lr] = av.w;
    const float* bp = Bw + (size_t)tid * 512 + k0;
#pragma unroll
    for (int q = 0; q < 4; q++) {
      float4 b4 = ld4(bp + 4 * q);
      Bs[4 * q + 0][tid] = b4.x; Bs[4 * q + 1][tid] = b4.y;
      Bs[4 * q + 2][tid] = b4.z; Bs[4 * q + 3][tid] = b4.w;
    }
    __syncthreads();
#pragma unroll
    for (int k = 0; k < 16; k++) {
      float4 a4 = *(const float4*)&As[k][ty << 2];
      float aa[4] = {a4.x, a4.y, a4.z, a4.w};
#pragma unroll
      for (int cc = 0; cc < 4; cc++) {
        float4 b4 = *(const float4*)&Bs[k][cc * 64 + (tx << 2)];
        float bb[4] = {b4.x, b4.y, b4.z, b4.w};
#pragma unroll
        for (int i = 0; i < 4; i++)
#pragma unroll
          for (int jj = 0; jj < 4; jj++) acc[i][cc * 4 + jj] += aa[i] * bb[jj];
      }
    }
    __syncthreads();
  }

#pragma unroll
  for (int i = 0; i < 4; i++) {
#pragma unroll
    for (int cc = 0; cc < 4; cc++) {
      int c0 = cc * 64 + (tx << 2);
      float4 o;
      o.x = acc[i][cc * 4 + 0] + bias[c0 + 0];
      o.y = acc[i][cc * 4 + 1] + bias[c0 + 1];
      o.z = acc[i][cc * 4 + 2] + bias[c0 + 2];
      o.w = acc[i][cc * 4 + 3] + bias[c0 + 3];
      *(float4*)&io[(size_t)(row0 + (ty << 2) + i) * 256 + c0] = o;
    }
  }
}

// ---------------------------------------------------------------------------
extern "C" void kernel_launch(void* const* d_in, const int* in_sizes, int n_in,
                              void* d_out, int out_size, void* d_ws, size_t ws_size,
                              hipStream_t stream)
{
  const float* x    = (const float*)d_in[0];
  const float* Wih0 = (const float*)d_in[1];
  const float* Whh0 = (const float*)d_in[2];
  const float* bih0 = (const float*)d_in[3];
  const float* bhh0 = (const float*)d_in[4];
  const float* Wih1 = (const float*)d_in[5];
  const float* Whh1 = (const float*)d_in[6];
  const float* bih1 = (const float*)d_in[7];
  const float* bhh1 = (const float*)d_in[8];
  const float* Wcq  = (const float*)d_in[9];
  const float* bcq  = (const float*)d_in[10];
  const float* keys = (const float*)d_in[11];
  const float* vals = (const float*)d_in[12];
  const float* Wout = (const float*)d_in[13];
  const float* bout = (const float*)d_in[14];
  const float* cw   = (const float*)d_in[15];
  const float* qw   = (const float*)d_in[16];
  float* out = (float*)d_out;

  // ws: [exchange 256 KB (dead after lstm2)] overlapped with enh [MT,256] f32.
  const size_t HE = (size_t)B_ * S_ * H_;
  if (ws_size < HE * sizeof(float)) return;   // 67.1 MB (round-4 proven OK)
  unsigned int* ex = (unsigned int*)d_ws;
  float* enh = (float*)d_ws;

  const int MT = B_ * S_;
  dim3 blk(256);

  hipMemsetAsync(ex, 0, (size_t)32 * 2048 * sizeof(unsigned int), stream);
  lstm2<<<dim3(256), blk, 0, stream>>>(x, Wih0, bih0, bhh0, Whh0,
                                       Wih1, bih1, bhh1, Whh1, out, ex);

  knn_enh<<<dim3(MT / 4), blk, 0, stream>>>(out, Wcq, bcq, keys, vals, qw, enh);

  gemm_cat<<<dim3(MT / 64), blk, 0, stream>>>(out, enh, Wout, bout, cw);
}